// Round 6
// baseline (671.969 us; speedup 1.0000x reference)
//
#include <hip/hip_runtime.h>
#include <hip/hip_bf16.h>
#include <stdint.h>

// ---------------- problem constants ----------------
constexpr int NN = 100000;     // nodes
constexpr int NE = 1600000;    // edges
constexpr int NG = 64;         // graphs
constexpr int S  = 192;        // row stride (elements) for node-feature buffers
constexpr int NB_SCAN = 98;    // ceil(100000/1024)
constexpr unsigned int ZOFF = (unsigned int)NN * 384u;   // byte offset of the zero row

// prep kernel grid sections (convx | indeg16+slot | convw(W0..W2) | nstart)
constexpr int PREP_CONVX_BLK = 12500;   // NN*32/256
constexpr int PREP_INDEG_BLK = 391;     // ceil(NE/16/256) — 16 edges/thread for atomic MLP
constexpr int PREP_CONVW_BLK = 384;     // (24576+36864+36864)/256
constexpr int PREP_GB_BLK    = 391;     // ceil(NN/256)
constexpr int PREP_GRID = PREP_CONVX_BLK + PREP_INDEG_BLK + PREP_CONVW_BLK + PREP_GB_BLK;

// E-GEMM geometry
constexpr int EG_BLOCKS = 391;            // ceil(NN/256), 256 src rows per block
constexpr int HROW = 50048;               // hist row length in u32 (EG_BLOCKS*256/2)

typedef __bf16 bf16x8 __attribute__((ext_vector_type(8)));
typedef float  f32x16 __attribute__((ext_vector_type(16)));
typedef float  f32x2  __attribute__((ext_vector_type(2)));

union U16x4 { uint4 u; bf16x8 b; };

// bf16(packed in uint halves) <-> f32 helpers
__device__ __forceinline__ float bl(unsigned int u) { return __uint_as_float(u << 16); }
__device__ __forceinline__ float bh(unsigned int u) { return __uint_as_float(u & 0xffff0000u); }
__device__ __forceinline__ float b16f(unsigned short u) { return __uint_as_float(((unsigned int)u) << 16); }
__device__ __forceinline__ unsigned int fb(float f) {  // f32 -> bf16 bits, RTNE
    unsigned int u = __float_as_uint(f);
    return (u + 0x7fffu + ((u >> 16) & 1u)) >> 16;
}
// packed bf16 relu: v_pk_max_f16 on raw bits decides on sign/zero only — exact for bf16.
__device__ __forceinline__ unsigned int prelu(unsigned int u) {
    unsigned int r;
    asm("v_pk_max_f16 %0, %1, %2" : "=v"(r) : "v"(u), "v"(0u));
    return r;
}
// two u16 counts -> packed bf16 pair (exact for counts <= 256)
__device__ __forceinline__ unsigned int cnt2bf(unsigned int h) {
    float f0 = (float)(h & 0xffffu);
    float f1 = (float)(h >> 16);
    return (__float_as_uint(f0) >> 16) | (__float_as_uint(f1) & 0xffff0000u);
}

// ---------------- fused preprocessing: convx | indeg+slot | convw | nstart ----------------
__global__ __launch_bounds__(256) void k_prep(const float* __restrict__ x,
                                              const int* __restrict__ ei,
                                              const int* __restrict__ bat,
                                              const float* __restrict__ W0, const float* __restrict__ W1,
                                              const float* __restrict__ W2,
                                              unsigned short* __restrict__ A_,
                                              int* __restrict__ indeg, int* __restrict__ slot,
                                              unsigned short* __restrict__ T0, unsigned short* __restrict__ T1,
                                              unsigned short* __restrict__ T2,
                                              int* __restrict__ nstart) {
    const int b = blockIdx.x;
    if (b < PREP_CONVX_BLK) {
        int id = b * 256 + threadIdx.x;
        if (id < 96) ((unsigned int*)(A_ + (size_t)NN * S))[id] = 0u;   // zero sentinel row
        int row = id >> 5, c4 = id & 31;
        float4 v = ((const float4*)x)[id];
        uint2 a;
        a.x = fb(v.x) | (fb(v.y) << 16);
        a.y = fb(v.z) | (fb(v.w) << 16);
        *(uint2*)(A_ + row * S + c4 * 4) = a;
    } else if (b < PREP_CONVX_BLK + PREP_INDEG_BLK) {
        // 16 edges/thread: 16 outstanding atomic-returns per lane (latency hiding)
        int id = (b - PREP_CONVX_BLK) * 256 + threadIdx.x;
        int e16 = id * 16;
        if (e16 < NE) {
            const int4* dp = (const int4*)(ei + NE + e16);
            int4 d0 = dp[0], d1 = dp[1], d2 = dp[2], d3 = dp[3];
            int4 s0, s1, s2, s3;
            s0.x = atomicAdd(&indeg[d0.x], 1);
            s0.y = atomicAdd(&indeg[d0.y], 1);
            s0.z = atomicAdd(&indeg[d0.z], 1);
            s0.w = atomicAdd(&indeg[d0.w], 1);
            s1.x = atomicAdd(&indeg[d1.x], 1);
            s1.y = atomicAdd(&indeg[d1.y], 1);
            s1.z = atomicAdd(&indeg[d1.z], 1);
            s1.w = atomicAdd(&indeg[d1.w], 1);
            s2.x = atomicAdd(&indeg[d2.x], 1);
            s2.y = atomicAdd(&indeg[d2.y], 1);
            s2.z = atomicAdd(&indeg[d2.z], 1);
            s2.w = atomicAdd(&indeg[d2.w], 1);
            s3.x = atomicAdd(&indeg[d3.x], 1);
            s3.y = atomicAdd(&indeg[d3.y], 1);
            s3.z = atomicAdd(&indeg[d3.z], 1);
            s3.w = atomicAdd(&indeg[d3.w], 1);
            int4* sp = (int4*)(slot + e16);
            sp[0] = s0; sp[1] = s1; sp[2] = s2; sp[3] = s3;
        }
    } else if (b < PREP_CONVX_BLK + PREP_INDEG_BLK + PREP_CONVW_BLK) {
        int id = (b - PREP_CONVX_BLK - PREP_INDEG_BLK) * 256 + threadIdx.x;
        const float* W; unsigned short* T; int N, base;
        if      (id < 24576) { W = W0; T = T0; N = 192; base = 0;     }
        else if (id < 61440) { W = W1; T = T1; N = 192; base = 24576; }
        else                 { W = W2; T = T2; N = 192; base = 61440; }
        int lid = id - base;
        int ci = lid >> 3, j = lid & 7;
        int kc = ci / N, n = ci % N;
        T[lid] = (unsigned short)fb(W[(kc * 8 + j) * N + n]);
    } else {
        // nstart[g] = first node n with bat[n] >= g (batch sorted); empty graphs ok
        int n = (b - PREP_CONVX_BLK - PREP_INDEG_BLK - PREP_CONVW_BLK) * 256 + threadIdx.x;
        if (n < NN) {
            int b0 = bat[n];
            int bprev = (n == 0) ? -1 : bat[n - 1];
            for (int g = bprev + 1; g <= b0; g++) nstart[g] = n;
            if (n == NN - 1)
                for (int g = b0 + 1; g < NG; g++) nstart[g] = NN;
        }
    }
}

// ---------------- scan of indeg -> offs (block-local; consumers add part[]) ----------------
__global__ __launch_bounds__(1024) void k_scan1(const int* __restrict__ indeg, int* __restrict__ offs,
                                                int* __restrict__ partials) {
    __shared__ int s[1024];
    int t = threadIdx.x;
    int gid = blockIdx.x * 1024 + t;
    int v = (gid < NN) ? indeg[gid] : 0;
    s[t] = v;
    __syncthreads();
    for (int d = 1; d < 1024; d <<= 1) {
        int tv = (t >= d) ? s[t - d] : 0;
        __syncthreads();
        s[t] += tv;
        __syncthreads();
    }
    if (gid < NN) offs[gid + 1] = s[t];
    if (t == 1023) partials[blockIdx.x] = s[1023];
}

__global__ __launch_bounds__(128) void k_scan2(int* __restrict__ offs, int* __restrict__ partials) {
    __shared__ int s[128];
    int t = threadIdx.x;
    int v = (t < NB_SCAN) ? partials[t] : 0;
    s[t] = v;
    __syncthreads();
    for (int d = 1; d < 128; d <<= 1) {
        int tv = (t >= d) ? s[t - d] : 0;
        __syncthreads();
        s[t] += tv;
        __syncthreads();
    }
    if (t < NB_SCAN) partials[t] = s[t] - v;
    if (t == 0) offs[0] = 0;
}

// true exclusive offset of node j (offs holds block-local inclusive scans)
__device__ __forceinline__ int toff(const int* __restrict__ offs, const int* __restrict__ part, int j) {
    return j ? (offs[j] + part[(j - 1) >> 10]) : 0;
}

// ---------------- atomic-free CSR fill ----------------
__global__ __launch_bounds__(256) void k_fill(const int* __restrict__ ei, const int* __restrict__ offs,
                                              const int* __restrict__ part,
                                              const int* __restrict__ slot, int* __restrict__ csr) {
    int e4 = (blockIdx.x * 256 + threadIdx.x) * 4;
    if (e4 >= NE) return;
    int4 sv = *(const int4*)(ei + e4);
    int4 dv = *(const int4*)(ei + NE + e4);
    int4 sl = *(const int4*)(slot + e4);
    csr[toff(offs, part, dv.x) + sl.x] = sv.x;
    csr[toff(offs, part, dv.y) + sl.y] = sv.y;
    csr[toff(offs, part, dv.z) + sl.z] = sv.z;
    csr[toff(offs, part, dv.w) + sl.w] = sv.w;
}

// ---------------- aggregation (layers 0..2) ----------------
__global__ __launch_bounds__(256, 8) void k_agg192(const unsigned short* __restrict__ Ain,
                                                   unsigned short* __restrict__ Yout,
                                                   const int* __restrict__ offs,
                                                   const int* __restrict__ part,
                                                   const int* __restrict__ indeg,
                                                   const int* __restrict__ csr) {
    const int w = threadIdx.x >> 6, lane = threadIdx.x & 63;
    const int i = __builtin_amdgcn_readfirstlane(blockIdx.x * 4 + w);
    const bool act = lane < 48;
    const int deg   = __builtin_amdgcn_readfirstlane(indeg[i]);
    const int start = __builtin_amdgcn_readfirstlane(toff(offs, part, i));
    const int fo = (act ? lane : 47) * 8;
    const char* Ab = (const char*)Ain;

    f32x2 A01, A23;
    {
        uint2 p = *(const uint2*)(Ab + (size_t)i * 384 + fo);
        const float ed = 1e-7f * (float)deg;
        A01 = (f32x2){bl(p.x) + ed, bh(p.x) + ed};
        A23 = (f32x2){bl(p.y) + ed, bh(p.y) + ed};
    }

    const int* ecsr = csr + start;
    for (int e = 0; e < deg; e += 16) {
        unsigned int off[16];
#pragma unroll
        for (int k = 0; k < 16; k++) {
            int v = ecsr[e + k];
            off[k] = (e + k < deg) ? (unsigned int)v * 384u : ZOFF;
        }
        uint2 p[16];
#pragma unroll
        for (int k = 0; k < 16; k++)
            p[k] = *(const uint2*)(Ab + (size_t)off[k] + fo);
#pragma unroll
        for (int k = 0; k < 16; k++) {
            unsigned int rx = prelu(p[k].x), ry = prelu(p[k].y);
            A01 += (f32x2){bl(rx), bh(rx)};
            A23 += (f32x2){bl(ry), bh(ry)};
        }
    }
    if (act) {
        uint2 o;
        o.x = fb(A01.x) | (fb(A01.y) << 16);
        o.y = fb(A23.x) | (fb(A23.y) << 16);
        *(uint2*)(Yout + (size_t)i * S + lane * 4) = o;
    }
}

__global__ __launch_bounds__(256, 8) void k_agg128(const unsigned short* __restrict__ Ain,
                                                   unsigned short* __restrict__ Yout,
                                                   const int* __restrict__ offs,
                                                   const int* __restrict__ part,
                                                   const int* __restrict__ indeg,
                                                   const int* __restrict__ csr) {
    const int w = threadIdx.x >> 6, lane = threadIdx.x & 63;
    const int i = __builtin_amdgcn_readfirstlane(blockIdx.x * 4 + w);
    const int deg   = __builtin_amdgcn_readfirstlane(indeg[i]);
    const int start = __builtin_amdgcn_readfirstlane(toff(offs, part, i));
    const int fo = lane * 4;
    const char* Ab = (const char*)Ain;

    f32x2 A01;
    {
        unsigned int p = *(const unsigned int*)(Ab + (size_t)i * 384 + fo);
        const float ed = 1e-7f * (float)deg;
        A01 = (f32x2){bl(p) + ed, bh(p) + ed};
    }

    const int* ecsr = csr + start;
    for (int e = 0; e < deg; e += 16) {
        unsigned int off[16];
#pragma unroll
        for (int k = 0; k < 16; k++) {
            int v = ecsr[e + k];
            off[k] = (e + k < deg) ? (unsigned int)v * 384u : ZOFF;
        }
        unsigned int q[16];
#pragma unroll
        for (int k = 0; k < 16; k++)
            q[k] = *(const unsigned int*)(Ab + (size_t)off[k] + fo);
#pragma unroll
        for (int k = 0; k < 16; k++) {
            unsigned int r = prelu(q[k]);
            A01 += (f32x2){bl(r), bh(r)};
        }
    }
    *(unsigned int*)(Yout + (size_t)i * S + lane * 2) =
        fb(A01.x) | (fb(A01.y) << 16);
}

// ---------------- GEMM: h = y @ W + b (layers 0..2) ----------------
template <int K, int N>
__global__ __launch_bounds__(256) void k_gemm(const unsigned short* __restrict__ Yin,
                                              const unsigned short* __restrict__ WtC,
                                              const float* __restrict__ bias,
                                              unsigned short* __restrict__ Aout) {
    static_assert(K % 16 == 0 && N % 32 == 0, "");
    const int w = threadIdx.x >> 6, lane = threadIdx.x & 63;
    const int rt = blockIdx.x * 4 + w;
    if (rt >= (NN / 32)) return;
    const int hl = lane >> 5, lr = lane & 31;
    const int row0 = rt * 32;
    f32x16 acc[N / 32];
#pragma unroll
    for (int c = 0; c < N / 32; c++)
#pragma unroll
        for (int r = 0; r < 16; r++) acc[c][r] = 0.f;

    const unsigned short* ap = Yin + (row0 + lr) * S + hl * 8;
    const uint4* b4 = (const uint4*)WtC;
#pragma unroll
    for (int ks = 0; ks < K / 16; ks++) {
        U16x4 a;
        a.u = *(const uint4*)(ap + ks * 16);
#pragma unroll
        for (int c = 0; c < N / 32; c++) {
            U16x4 b;
            b.u = b4[(ks * 2 + hl) * N + c * 32 + lr];
            acc[c] = __builtin_amdgcn_mfma_f32_32x32x16_bf16(a.b, b.b, acc[c], 0, 0, 0);
        }
    }
#pragma unroll
    for (int c = 0; c < N / 32; c++) {
        const int col = c * 32 + lr;
        const float bc = bias[col];
#pragma unroll
        for (int r = 0; r < 16; r++) {
            const int row = row0 + (r & 3) + 8 * (r >> 2) + 4 * hl;
            Aout[row * S + col] = (unsigned short)fb(acc[c][r] + bc);
        }
    }
}

// ---------------- fused hist + pool (both depend only on layer-2 output) ----------------
// Blocks 0..255: hist (g=b>>2, quarter q=b&3 of the graph's csr range, single pass,
// full-row atomics; hist pre-zeroed by the mid-stream memset).
// Blocks 256..2255: pooling over x3, 50 nodes/block (4x parallelism of round-5).
__global__ __launch_bounds__(256) void k_histpool(const int* __restrict__ csr,
                                                  const int* __restrict__ offs,
                                                  const int* __restrict__ part,
                                                  const int* __restrict__ nstart,
                                                  unsigned int* __restrict__ hist,
                                                  const unsigned short* __restrict__ X3,
                                                  const int* __restrict__ bat,
                                                  const int* __restrict__ indeg,
                                                  float* __restrict__ sums, float* __restrict__ cnt,
                                                  float* __restrict__ degsum) {
    const int b = blockIdx.x;
    if (b < 256) {
        const int g = b >> 2, q = b & 3;
        const int s0 = toff(offs, part, nstart[g]);
        const int s1 = (g == NG - 1) ? NE : toff(offs, part, nstart[g + 1]);
        const int len = s1 - s0;
        const int qs = s0 + (int)(((long long)len * q) >> 2);
        const int qe = s0 + (int)(((long long)len * (q + 1)) >> 2);
        unsigned int* hrow = hist + (size_t)g * HROW;
        for (int p = qs + threadIdx.x; p < qe; p += 256) {
            int src = csr[p];
            atomicAdd(&hrow[(unsigned int)src >> 1], 1u << (16 * (src & 1)));
        }
    } else {
        const int pb = b - 256;        // 2000 blocks x 50 nodes
        const int f = threadIdx.x;     // 192 features (64 lanes idle)
        if (f >= 192) return;
        int n0 = pb * 50;
        int n1 = min(n0 + 50, NN);
        int cur = bat[n0];
        float acc = 0.f;
        int run = 0, dacc = 0;
        for (int n = n0; n < n1; n++) {
            int g = bat[n];
            if (g != cur) {
                atomicAdd(&sums[cur * 192 + f], acc);
                if (f == 0) { atomicAdd(&cnt[cur], (float)run); atomicAdd(&degsum[cur], (float)dacc); }
                acc = 0.f; run = 0; dacc = 0; cur = g;
            }
            acc += b16f(X3[(size_t)n * S + f]);
            run++;
            if (f == 0) dacc += indeg[n];
        }
        atomicAdd(&sums[cur * 192 + f], acc);
        if (f == 0) { atomicAdd(&cnt[cur], (float)run); atomicAdd(&degsum[cur], (float)dacc); }
    }
}

// ---------------- layer-3 E-GEMM: P[g][f] += count(j->g) * relu(x3[j][f]) ----------------
__global__ __launch_bounds__(384) void k_egemm(const unsigned short* __restrict__ X3,
                                               const unsigned int* __restrict__ hist,
                                               float* __restrict__ partials) {
    const int wv = threadIdx.x >> 6, lane = threadIdx.x & 63;
    const int b = blockIdx.x;
    const int j0 = b * 256;
    const int hl = lane >> 5, lr = lane & 31;
    const int feat = wv * 32 + lr;
    f32x16 acc[2];
#pragma unroll
    for (int m = 0; m < 2; m++)
#pragma unroll
        for (int r = 0; r < 16; r++) acc[m][r] = 0.f;

    for (int kk = 0; kk < 16; kk++) {
        const int jh = (j0 >> 1) + kk * 8 + hl * 4;
        U16x4 af[2];
#pragma unroll
        for (int m = 0; m < 2; m++) {
            uint4 h = *(const uint4*)(hist + (size_t)(m * 32 + lr) * HROW + jh);
            af[m].u = (uint4){cnt2bf(h.x), cnt2bf(h.y), cnt2bf(h.z), cnt2bf(h.w)};
        }
        U16x4 bf;
#pragma unroll
        for (int tp = 0; tp < 4; tp++) {
            int je = j0 + kk * 16 + hl * 8 + tp * 2;
            int ja = min(je, NN), jb = min(je + 1, NN);   // sentinel zero row
            unsigned int u0 = X3[(size_t)ja * S + feat];
            unsigned int u1 = X3[(size_t)jb * S + feat];
            ((unsigned int*)&bf.u)[tp] = prelu(u0 | (u1 << 16));
        }
#pragma unroll
        for (int m = 0; m < 2; m++)
            acc[m] = __builtin_amdgcn_mfma_f32_32x32x16_bf16(af[m].b, bf.b, acc[m], 0, 0, 0);
    }
    float* pb = partials + (size_t)b * 12288;
#pragma unroll
    for (int m = 0; m < 2; m++)
#pragma unroll
        for (int r = 0; r < 16; r++) {
            const int g = m * 32 + (r & 3) + 8 * (r >> 2) + 4 * hl;
            pb[g * 192 + feat] = acc[m][r];
        }
}

// ---------------- head (fused partial-reduce + 2-layer MLP + log_softmax) ----------------
__global__ __launch_bounds__(192) void k_head(const float* __restrict__ sums,
                                              const float* __restrict__ partials,
                                              const float* __restrict__ cnt, const float* __restrict__ degsum,
                                              const float* __restrict__ W3, const float* __restrict__ b3,
                                              const float* __restrict__ Wfc, const float* __restrict__ bfc,
                                              float* __restrict__ out) {
    __shared__ float py[192];
    __shared__ float tl[128];
    __shared__ float lg[10];
    const int g = blockIdx.x, t = threadIdx.x;   // 192 threads = 192 feats
    const float inv = 1.f / fmaxf(cnt[g], 1.f);
    const float ed = 1e-7f * degsum[g];
    // msg[g][t] = sum over 391 partial blocks (4 accumulators for MLP)
    const float* pp = partials + g * 192 + t;
    float s0 = 0.f, s1 = 0.f, s2 = 0.f, s3 = 0.f;
    int p = 0;
    for (; p + 4 <= EG_BLOCKS; p += 4) {
        s0 += pp[(size_t)(p + 0) * 12288];
        s1 += pp[(size_t)(p + 1) * 12288];
        s2 += pp[(size_t)(p + 2) * 12288];
        s3 += pp[(size_t)(p + 3) * 12288];
    }
    for (; p < EG_BLOCKS; p++) s0 += pp[(size_t)p * 12288];
    py[t] = (sums[g * 192 + t] + ((s0 + s1) + (s2 + s3)) + ed) * inv;
    __syncthreads();
    if (t < 128) {
        float tf = b3[t];
        for (int k = 0; k < 192; k++) tf += py[k] * W3[k * 128 + t];
        tl[t] = tf;
    }
    __syncthreads();
    if (t < 10) {
        float s = bfc[t];
        for (int f = 0; f < 128; f++) s += tl[f] * Wfc[f * 10 + t];
        lg[t] = s;
    }
    __syncthreads();
    if (t < 10) {
        float m = lg[0];
        for (int k = 1; k < 10; k++) m = fmaxf(m, lg[k]);
        float se = 0.f;
        for (int k = 0; k < 10; k++) se += expf(lg[k] - m);
        out[g * 10 + t] = lg[t] - m - logf(se);
    }
}

// ---------------- workspace layout (bytes) ----------------
// Parity: agg always A0 -> A1 (y), gemm A1 -> A0 (x). x3 ends in A0; y2 (A1) dead after
// the L2 gemm, so hist/parts reuse the A1 region (hist zeroed by mid-stream memset).
// INDEG..DEGS contiguous -> single 449,664 B memset.
constexpr size_t A0_OFF     = 0;                    // 38,400,384 (incl zero row NN)
constexpr size_t A1_OFF     = 38400384;             // 38,400,000: slot -> y -> hist/partials
constexpr size_t HIST_REL   = 0;                    // 12,812,288 (64*50048*4)
constexpr size_t PARTS_REL  = 12812288;             // 19,218,432 (391*12288*4) -> ends 32,030,720
constexpr size_t CSR_OFF    = 76800384;             // 6,400,000
constexpr size_t OFFS_OFF   = 83200384;             // 400,128
constexpr size_t INDEG_OFF  = 83600512;             // 400,000
constexpr size_t SUMS_OFF   = 84000512;             // 49,152
constexpr size_t CNT_OFF    = 84049664;             // 256
constexpr size_t DEGS_OFF   = 84049920;             // 256 -> zero-region ends 84,050,176
constexpr size_t PART_OFF   = 84050176;             // 512
constexpr size_t NSTART_OFF = 84050688;             // 256
constexpr size_t WT0_OFF    = 84050944;             // 49,152
constexpr size_t WT1_OFF    = 84100096;             // 73,728
constexpr size_t WT2_OFF    = 84173824;             // 73,728 -> ends 84,247,552

extern "C" void kernel_launch(void* const* d_in, const int* in_sizes, int n_in,
                              void* d_out, int out_size, void* d_ws, size_t ws_size,
                              hipStream_t stream) {
    const float* x   = (const float*)d_in[0];
    const float* W0  = (const float*)d_in[1];
    const float* b0  = (const float*)d_in[2];
    const float* W1  = (const float*)d_in[3];
    const float* b1  = (const float*)d_in[4];
    const float* W2  = (const float*)d_in[5];
    const float* b2  = (const float*)d_in[6];
    const float* W3  = (const float*)d_in[7];
    const float* b3  = (const float*)d_in[8];
    const float* Wfc = (const float*)d_in[9];
    const float* bfc = (const float*)d_in[10];
    const int*   ei  = (const int*)d_in[11];
    const int*   bat = (const int*)d_in[12];
    float* out = (float*)d_out;

    char* ws = (char*)d_ws;
    unsigned short* A0  = (unsigned short*)(ws + A0_OFF);
    unsigned short* A1  = (unsigned short*)(ws + A1_OFF);
    int* slot   = (int*)(ws + A1_OFF);
    unsigned int* hist  = (unsigned int*)(ws + A1_OFF + HIST_REL);
    float* parts        = (float*)(ws + A1_OFF + PARTS_REL);
    int* csr    = (int*)(ws + CSR_OFF);
    int* offs   = (int*)(ws + OFFS_OFF);
    int* indeg  = (int*)(ws + INDEG_OFF);
    int* part   = (int*)(ws + PART_OFF);
    int* nstart = (int*)(ws + NSTART_OFF);
    unsigned short* Wt0 = (unsigned short*)(ws + WT0_OFF);
    unsigned short* Wt1 = (unsigned short*)(ws + WT1_OFF);
    unsigned short* Wt2 = (unsigned short*)(ws + WT2_OFF);
    float* sums   = (float*)(ws + SUMS_OFF);
    float* cnt    = (float*)(ws + CNT_OFF);
    float* degsum = (float*)(ws + DEGS_OFF);

    // one memset: indeg + sums + cnt + degsum (contiguous 449,664 B)
    hipMemsetAsync(ws + INDEG_OFF, 0, 449664, stream);

    // fused preprocessing
    k_prep<<<PREP_GRID, 256, 0, stream>>>(x, ei, bat, W0, W1, W2, A0, indeg, slot,
                                          Wt0, Wt1, Wt2, nstart);

    // block-local scan + block-partial scan (consumers add part[])
    k_scan1<<<NB_SCAN, 1024, 0, stream>>>(indeg, offs, part);
    k_scan2<<<1, 128, 0, stream>>>(offs, part);
    k_fill<<<(NE / 4 + 255) / 256, 256, 0, stream>>>(ei, offs, part, slot, csr);

    const int AGG_GRID  = NN / 4;                   // 25000 blocks
    const int GEMM_GRID = (NN / 32 + 3) / 4;        // 782 blocks

    // layers 0..2 (agg A0 -> A1, gemm A1 -> A0)
    k_agg128<<<AGG_GRID, 256, 0, stream>>>(A0, A1, offs, part, indeg, csr);
    k_gemm<128, 192><<<GEMM_GRID, 256, 0, stream>>>(A1, Wt0, b0, A0);
    k_agg192<<<AGG_GRID, 256, 0, stream>>>(A0, A1, offs, part, indeg, csr);
    k_gemm<192, 192><<<GEMM_GRID, 256, 0, stream>>>(A1, Wt1, b1, A0);
    k_agg192<<<AGG_GRID, 256, 0, stream>>>(A0, A1, offs, part, indeg, csr);
    k_gemm<192, 192><<<GEMM_GRID, 256, 0, stream>>>(A1, Wt2, b2, A0);   // x3 -> A0

    // layer 3 via linearity: pooled(y3) = pooled(x3) + eps*degsum + E @ relu(x3)
    hipMemsetAsync(ws + A1_OFF + HIST_REL, 0, 12812288, stream);        // y2 dead; reuse A1
    k_histpool<<<2256, 256, 0, stream>>>(csr, offs, part, nstart, hist, A0, bat, indeg,
                                         sums, cnt, degsum);
    k_egemm<<<EG_BLOCKS, 384, 0, stream>>>(A0, hist, parts);
    k_head<<<NG, 192, 0, stream>>>(sums, parts, cnt, degsum, W3, b3, Wfc, bfc, out);
}

// Round 7
// 646.689 us; speedup vs baseline: 1.0391x; 1.0391x over previous
//
#include <hip/hip_runtime.h>
#include <hip/hip_bf16.h>
#include <stdint.h>

// ---------------- problem constants ----------------
constexpr int NN = 100000;     // nodes
constexpr int NE = 1600000;    // edges
constexpr int NG = 64;         // graphs
constexpr int S  = 192;        // row stride (elements) for node-feature buffers
constexpr int NB_SCAN = 98;    // ceil(100000/1024)
constexpr unsigned int ZOFF = (unsigned int)NN * 384u;   // byte offset of the zero row

// prep kernel grid sections (indeg+slot FIRST | convx | convw(W0..W2) | nstart)
// indeg first: its returning-atomic latency hides under the convx streaming blocks
// that fill the CUs behind it (round-6 lesson: atomics alone at the tail = exposed).
constexpr int PREP_INDEG_BLK = 1563;    // ceil(NE/4/256), 4 edges/thread (round-5 proven)
constexpr int PREP_CONVX_BLK = 12500;   // NN*32/256
constexpr int PREP_CONVW_BLK = 384;     // (24576+36864+36864)/256
constexpr int PREP_GB_BLK    = 391;     // ceil(NN/256)
constexpr int PREP_GRID = PREP_INDEG_BLK + PREP_CONVX_BLK + PREP_CONVW_BLK + PREP_GB_BLK;

// E-GEMM geometry
constexpr int EG_BLOCKS = 391;            // ceil(NN/256), 256 src rows per block
constexpr int HROW = 50048;               // hist row length in u32 (EG_BLOCKS*256/2)

typedef __bf16 bf16x8 __attribute__((ext_vector_type(8)));
typedef float  f32x16 __attribute__((ext_vector_type(16)));
typedef float  f32x2  __attribute__((ext_vector_type(2)));

union U16x4 { uint4 u; bf16x8 b; };

// bf16(packed in uint halves) <-> f32 helpers
__device__ __forceinline__ float bl(unsigned int u) { return __uint_as_float(u << 16); }
__device__ __forceinline__ float bh(unsigned int u) { return __uint_as_float(u & 0xffff0000u); }
__device__ __forceinline__ float b16f(unsigned short u) { return __uint_as_float(((unsigned int)u) << 16); }
__device__ __forceinline__ unsigned int fb(float f) {  // f32 -> bf16 bits, RTNE
    unsigned int u = __float_as_uint(f);
    return (u + 0x7fffu + ((u >> 16) & 1u)) >> 16;
}
// packed bf16 relu: v_pk_max_f16 on raw bits decides on sign/zero only — exact for bf16.
__device__ __forceinline__ unsigned int prelu(unsigned int u) {
    unsigned int r;
    asm("v_pk_max_f16 %0, %1, %2" : "=v"(r) : "v"(u), "v"(0u));
    return r;
}
// two u16 counts -> packed bf16 pair (exact for counts <= 256)
__device__ __forceinline__ unsigned int cnt2bf(unsigned int h) {
    float f0 = (float)(h & 0xffffu);
    float f1 = (float)(h >> 16);
    return (__float_as_uint(f0) >> 16) | (__float_as_uint(f1) & 0xffff0000u);
}

// ---------------- fused preprocessing: indeg+slot | convx | convw | nstart ----------------
__global__ __launch_bounds__(256) void k_prep(const float* __restrict__ x,
                                              const int* __restrict__ ei,
                                              const int* __restrict__ bat,
                                              const float* __restrict__ W0, const float* __restrict__ W1,
                                              const float* __restrict__ W2,
                                              unsigned short* __restrict__ A_,
                                              int* __restrict__ indeg, int* __restrict__ slot,
                                              unsigned short* __restrict__ T0, unsigned short* __restrict__ T1,
                                              unsigned short* __restrict__ T2,
                                              int* __restrict__ nstart) {
    const int b = blockIdx.x;
    if (b < PREP_INDEG_BLK) {
        int e4 = (b * 256 + threadIdx.x) * 4;
        if (e4 < NE) {
            int4 d = *(const int4*)(ei + NE + e4);
            int4 sl;
            sl.x = atomicAdd(&indeg[d.x], 1);
            sl.y = atomicAdd(&indeg[d.y], 1);
            sl.z = atomicAdd(&indeg[d.z], 1);
            sl.w = atomicAdd(&indeg[d.w], 1);
            *(int4*)(slot + e4) = sl;
        }
    } else if (b < PREP_INDEG_BLK + PREP_CONVX_BLK) {
        int id = (b - PREP_INDEG_BLK) * 256 + threadIdx.x;
        if (id < 96) ((unsigned int*)(A_ + (size_t)NN * S))[id] = 0u;   // zero sentinel row
        int row = id >> 5, c4 = id & 31;
        float4 v = ((const float4*)x)[id];
        uint2 a;
        a.x = fb(v.x) | (fb(v.y) << 16);
        a.y = fb(v.z) | (fb(v.w) << 16);
        *(uint2*)(A_ + row * S + c4 * 4) = a;
    } else if (b < PREP_INDEG_BLK + PREP_CONVX_BLK + PREP_CONVW_BLK) {
        int id = (b - PREP_INDEG_BLK - PREP_CONVX_BLK) * 256 + threadIdx.x;
        const float* W; unsigned short* T; int N, base;
        if      (id < 24576) { W = W0; T = T0; N = 192; base = 0;     }
        else if (id < 61440) { W = W1; T = T1; N = 192; base = 24576; }
        else                 { W = W2; T = T2; N = 192; base = 61440; }
        int lid = id - base;
        int ci = lid >> 3, j = lid & 7;
        int kc = ci / N, n = ci % N;
        T[lid] = (unsigned short)fb(W[(kc * 8 + j) * N + n]);
    } else {
        // nstart[g] = first node n with bat[n] >= g (batch sorted); empty graphs ok
        int n = (b - PREP_INDEG_BLK - PREP_CONVX_BLK - PREP_CONVW_BLK) * 256 + threadIdx.x;
        if (n < NN) {
            int b0 = bat[n];
            int bprev = (n == 0) ? -1 : bat[n - 1];
            for (int g = bprev + 1; g <= b0; g++) nstart[g] = n;
            if (n == NN - 1)
                for (int g = b0 + 1; g < NG; g++) nstart[g] = NN;
        }
    }
}

// ---------------- scan of indeg -> offs (block-local; consumers add part[]) ----------------
__global__ __launch_bounds__(1024) void k_scan1(const int* __restrict__ indeg, int* __restrict__ offs,
                                                int* __restrict__ partials) {
    __shared__ int s[1024];
    int t = threadIdx.x;
    int gid = blockIdx.x * 1024 + t;
    int v = (gid < NN) ? indeg[gid] : 0;
    s[t] = v;
    __syncthreads();
    for (int d = 1; d < 1024; d <<= 1) {
        int tv = (t >= d) ? s[t - d] : 0;
        __syncthreads();
        s[t] += tv;
        __syncthreads();
    }
    if (gid < NN) offs[gid + 1] = s[t];
    if (t == 1023) partials[blockIdx.x] = s[1023];
}

__global__ __launch_bounds__(128) void k_scan2(int* __restrict__ offs, int* __restrict__ partials) {
    __shared__ int s[128];
    int t = threadIdx.x;
    int v = (t < NB_SCAN) ? partials[t] : 0;
    s[t] = v;
    __syncthreads();
    for (int d = 1; d < 128; d <<= 1) {
        int tv = (t >= d) ? s[t - d] : 0;
        __syncthreads();
        s[t] += tv;
        __syncthreads();
    }
    if (t < NB_SCAN) partials[t] = s[t] - v;
    if (t == 0) offs[0] = 0;
}

// true exclusive offset of node j (offs holds block-local inclusive scans)
__device__ __forceinline__ int toff(const int* __restrict__ offs, const int* __restrict__ part, int j) {
    return j ? (offs[j] + part[(j - 1) >> 10]) : 0;
}

// ---------------- atomic-free CSR fill ----------------
__global__ __launch_bounds__(256) void k_fill(const int* __restrict__ ei, const int* __restrict__ offs,
                                              const int* __restrict__ part,
                                              const int* __restrict__ slot, int* __restrict__ csr) {
    int e4 = (blockIdx.x * 256 + threadIdx.x) * 4;
    if (e4 >= NE) return;
    int4 sv = *(const int4*)(ei + e4);
    int4 dv = *(const int4*)(ei + NE + e4);
    int4 sl = *(const int4*)(slot + e4);
    csr[toff(offs, part, dv.x) + sl.x] = sv.x;
    csr[toff(offs, part, dv.y) + sl.y] = sv.y;
    csr[toff(offs, part, dv.z) + sl.z] = sv.z;
    csr[toff(offs, part, dv.w) + sl.w] = sv.w;
}

// ---------------- aggregation (layers 0..2) ----------------
__global__ __launch_bounds__(256, 8) void k_agg192(const unsigned short* __restrict__ Ain,
                                                   unsigned short* __restrict__ Yout,
                                                   const int* __restrict__ offs,
                                                   const int* __restrict__ part,
                                                   const int* __restrict__ indeg,
                                                   const int* __restrict__ csr) {
    const int w = threadIdx.x >> 6, lane = threadIdx.x & 63;
    const int i = __builtin_amdgcn_readfirstlane(blockIdx.x * 4 + w);
    const bool act = lane < 48;
    const int deg   = __builtin_amdgcn_readfirstlane(indeg[i]);
    const int start = __builtin_amdgcn_readfirstlane(toff(offs, part, i));
    const int fo = (act ? lane : 47) * 8;
    const char* Ab = (const char*)Ain;

    f32x2 A01, A23;
    {
        uint2 p = *(const uint2*)(Ab + (size_t)i * 384 + fo);
        const float ed = 1e-7f * (float)deg;
        A01 = (f32x2){bl(p.x) + ed, bh(p.x) + ed};
        A23 = (f32x2){bl(p.y) + ed, bh(p.y) + ed};
    }

    const int* ecsr = csr + start;
    for (int e = 0; e < deg; e += 16) {
        unsigned int off[16];
#pragma unroll
        for (int k = 0; k < 16; k++) {
            int v = ecsr[e + k];
            off[k] = (e + k < deg) ? (unsigned int)v * 384u : ZOFF;
        }
        uint2 p[16];
#pragma unroll
        for (int k = 0; k < 16; k++)
            p[k] = *(const uint2*)(Ab + (size_t)off[k] + fo);
#pragma unroll
        for (int k = 0; k < 16; k++) {
            unsigned int rx = prelu(p[k].x), ry = prelu(p[k].y);
            A01 += (f32x2){bl(rx), bh(rx)};
            A23 += (f32x2){bl(ry), bh(ry)};
        }
    }
    if (act) {
        uint2 o;
        o.x = fb(A01.x) | (fb(A01.y) << 16);
        o.y = fb(A23.x) | (fb(A23.y) << 16);
        *(uint2*)(Yout + (size_t)i * S + lane * 4) = o;
    }
}

__global__ __launch_bounds__(256, 8) void k_agg128(const unsigned short* __restrict__ Ain,
                                                   unsigned short* __restrict__ Yout,
                                                   const int* __restrict__ offs,
                                                   const int* __restrict__ part,
                                                   const int* __restrict__ indeg,
                                                   const int* __restrict__ csr) {
    const int w = threadIdx.x >> 6, lane = threadIdx.x & 63;
    const int i = __builtin_amdgcn_readfirstlane(blockIdx.x * 4 + w);
    const int deg   = __builtin_amdgcn_readfirstlane(indeg[i]);
    const int start = __builtin_amdgcn_readfirstlane(toff(offs, part, i));
    const int fo = lane * 4;
    const char* Ab = (const char*)Ain;

    f32x2 A01;
    {
        unsigned int p = *(const unsigned int*)(Ab + (size_t)i * 384 + fo);
        const float ed = 1e-7f * (float)deg;
        A01 = (f32x2){bl(p) + ed, bh(p) + ed};
    }

    const int* ecsr = csr + start;
    for (int e = 0; e < deg; e += 16) {
        unsigned int off[16];
#pragma unroll
        for (int k = 0; k < 16; k++) {
            int v = ecsr[e + k];
            off[k] = (e + k < deg) ? (unsigned int)v * 384u : ZOFF;
        }
        unsigned int q[16];
#pragma unroll
        for (int k = 0; k < 16; k++)
            q[k] = *(const unsigned int*)(Ab + (size_t)off[k] + fo);
#pragma unroll
        for (int k = 0; k < 16; k++) {
            unsigned int r = prelu(q[k]);
            A01 += (f32x2){bl(r), bh(r)};
        }
    }
    *(unsigned int*)(Yout + (size_t)i * S + lane * 2) =
        fb(A01.x) | (fb(A01.y) << 16);
}

// ---------------- GEMM: h = y @ W + b (layers 0..2) ----------------
template <int K, int N>
__global__ __launch_bounds__(256) void k_gemm(const unsigned short* __restrict__ Yin,
                                              const unsigned short* __restrict__ WtC,
                                              const float* __restrict__ bias,
                                              unsigned short* __restrict__ Aout) {
    static_assert(K % 16 == 0 && N % 32 == 0, "");
    const int w = threadIdx.x >> 6, lane = threadIdx.x & 63;
    const int rt = blockIdx.x * 4 + w;
    if (rt >= (NN / 32)) return;
    const int hl = lane >> 5, lr = lane & 31;
    const int row0 = rt * 32;
    f32x16 acc[N / 32];
#pragma unroll
    for (int c = 0; c < N / 32; c++)
#pragma unroll
        for (int r = 0; r < 16; r++) acc[c][r] = 0.f;

    const unsigned short* ap = Yin + (row0 + lr) * S + hl * 8;
    const uint4* b4 = (const uint4*)WtC;
#pragma unroll
    for (int ks = 0; ks < K / 16; ks++) {
        U16x4 a;
        a.u = *(const uint4*)(ap + ks * 16);
#pragma unroll
        for (int c = 0; c < N / 32; c++) {
            U16x4 b;
            b.u = b4[(ks * 2 + hl) * N + c * 32 + lr];
            acc[c] = __builtin_amdgcn_mfma_f32_32x32x16_bf16(a.b, b.b, acc[c], 0, 0, 0);
        }
    }
#pragma unroll
    for (int c = 0; c < N / 32; c++) {
        const int col = c * 32 + lr;
        const float bc = bias[col];
#pragma unroll
        for (int r = 0; r < 16; r++) {
            const int row = row0 + (r & 3) + 8 * (r >> 2) + 4 * hl;
            Aout[row * S + col] = (unsigned short)fb(acc[c][r] + bc);
        }
    }
}

// ---------------- fused hist + pool (both depend only on layer-2 output) ----------------
// Blocks 0..255: hist (g=b>>2, quarter q=b&3 of the graph's csr range, single pass,
// full-row atomics; hist pre-zeroed by the mid-stream memset).
// Blocks 256..2255: pooling over x3, 50 nodes/block.
__global__ __launch_bounds__(256) void k_histpool(const int* __restrict__ csr,
                                                  const int* __restrict__ offs,
                                                  const int* __restrict__ part,
                                                  const int* __restrict__ nstart,
                                                  unsigned int* __restrict__ hist,
                                                  const unsigned short* __restrict__ X3,
                                                  const int* __restrict__ bat,
                                                  const int* __restrict__ indeg,
                                                  float* __restrict__ sums, float* __restrict__ cnt,
                                                  float* __restrict__ degsum) {
    const int b = blockIdx.x;
    if (b < 256) {
        const int g = b >> 2, q = b & 3;
        const int s0 = toff(offs, part, nstart[g]);
        const int s1 = (g == NG - 1) ? NE : toff(offs, part, nstart[g + 1]);
        const int len = s1 - s0;
        const int qs = s0 + (int)(((long long)len * q) >> 2);
        const int qe = s0 + (int)(((long long)len * (q + 1)) >> 2);
        unsigned int* hrow = hist + (size_t)g * HROW;
        for (int p = qs + threadIdx.x; p < qe; p += 256) {
            int src = csr[p];
            atomicAdd(&hrow[(unsigned int)src >> 1], 1u << (16 * (src & 1)));
        }
    } else {
        const int pb = b - 256;        // 2000 blocks x 50 nodes
        const int f = threadIdx.x;     // 192 features (64 lanes idle)
        if (f >= 192) return;
        int n0 = pb * 50;
        int n1 = min(n0 + 50, NN);
        int cur = bat[n0];
        float acc = 0.f;
        int run = 0, dacc = 0;
        for (int n = n0; n < n1; n++) {
            int g = bat[n];
            if (g != cur) {
                atomicAdd(&sums[cur * 192 + f], acc);
                if (f == 0) { atomicAdd(&cnt[cur], (float)run); atomicAdd(&degsum[cur], (float)dacc); }
                acc = 0.f; run = 0; dacc = 0; cur = g;
            }
            acc += b16f(X3[(size_t)n * S + f]);
            run++;
            if (f == 0) dacc += indeg[n];
        }
        atomicAdd(&sums[cur * 192 + f], acc);
        if (f == 0) { atomicAdd(&cnt[cur], (float)run); atomicAdd(&degsum[cur], (float)dacc); }
    }
}

// ---------------- layer-3 E-GEMM: P[g][f] += count(j->g) * relu(x3[j][f]) ----------------
__global__ __launch_bounds__(384) void k_egemm(const unsigned short* __restrict__ X3,
                                               const unsigned int* __restrict__ hist,
                                               float* __restrict__ partials) {
    const int wv = threadIdx.x >> 6, lane = threadIdx.x & 63;
    const int b = blockIdx.x;
    const int j0 = b * 256;
    const int hl = lane >> 5, lr = lane & 31;
    const int feat = wv * 32 + lr;
    f32x16 acc[2];
#pragma unroll
    for (int m = 0; m < 2; m++)
#pragma unroll
        for (int r = 0; r < 16; r++) acc[m][r] = 0.f;

    for (int kk = 0; kk < 16; kk++) {
        const int jh = (j0 >> 1) + kk * 8 + hl * 4;
        U16x4 af[2];
#pragma unroll
        for (int m = 0; m < 2; m++) {
            uint4 h = *(const uint4*)(hist + (size_t)(m * 32 + lr) * HROW + jh);
            af[m].u = (uint4){cnt2bf(h.x), cnt2bf(h.y), cnt2bf(h.z), cnt2bf(h.w)};
        }
        U16x4 bf;
#pragma unroll
        for (int tp = 0; tp < 4; tp++) {
            int je = j0 + kk * 16 + hl * 8 + tp * 2;
            int ja = min(je, NN), jb = min(je + 1, NN);   // sentinel zero row
            unsigned int u0 = X3[(size_t)ja * S + feat];
            unsigned int u1 = X3[(size_t)jb * S + feat];
            ((unsigned int*)&bf.u)[tp] = prelu(u0 | (u1 << 16));
        }
#pragma unroll
        for (int m = 0; m < 2; m++)
            acc[m] = __builtin_amdgcn_mfma_f32_32x32x16_bf16(af[m].b, bf.b, acc[m], 0, 0, 0);
    }
    float* pb = partials + (size_t)b * 12288;
#pragma unroll
    for (int m = 0; m < 2; m++)
#pragma unroll
        for (int r = 0; r < 16; r++) {
            const int g = m * 32 + (r & 3) + 8 * (r >> 2) + 4 * hl;
            pb[g * 192 + feat] = acc[m][r];
        }
}

// ---------------- head (fused partial-reduce + 2-layer MLP + log_softmax) ----------------
__global__ __launch_bounds__(192) void k_head(const float* __restrict__ sums,
                                              const float* __restrict__ partials,
                                              const float* __restrict__ cnt, const float* __restrict__ degsum,
                                              const float* __restrict__ W3, const float* __restrict__ b3,
                                              const float* __restrict__ Wfc, const float* __restrict__ bfc,
                                              float* __restrict__ out) {
    __shared__ float py[192];
    __shared__ float tl[128];
    __shared__ float lg[10];
    const int g = blockIdx.x, t = threadIdx.x;   // 192 threads = 192 feats
    const float inv = 1.f / fmaxf(cnt[g], 1.f);
    const float ed = 1e-7f * degsum[g];
    // msg[g][t] = sum over 391 partial blocks (4 accumulators for MLP)
    const float* pp = partials + g * 192 + t;
    float s0 = 0.f, s1 = 0.f, s2 = 0.f, s3 = 0.f;
    int p = 0;
    for (; p + 4 <= EG_BLOCKS; p += 4) {
        s0 += pp[(size_t)(p + 0) * 12288];
        s1 += pp[(size_t)(p + 1) * 12288];
        s2 += pp[(size_t)(p + 2) * 12288];
        s3 += pp[(size_t)(p + 3) * 12288];
    }
    for (; p < EG_BLOCKS; p++) s0 += pp[(size_t)p * 12288];
    py[t] = (sums[g * 192 + t] + ((s0 + s1) + (s2 + s3)) + ed) * inv;
    __syncthreads();
    if (t < 128) {
        float tf = b3[t];
        for (int k = 0; k < 192; k++) tf += py[k] * W3[k * 128 + t];
        tl[t] = tf;
    }
    __syncthreads();
    if (t < 10) {
        float s = bfc[t];
        for (int f = 0; f < 128; f++) s += tl[f] * Wfc[f * 10 + t];
        lg[t] = s;
    }
    __syncthreads();
    if (t < 10) {
        float m = lg[0];
        for (int k = 1; k < 10; k++) m = fmaxf(m, lg[k]);
        float se = 0.f;
        for (int k = 0; k < 10; k++) se += expf(lg[k] - m);
        out[g * 10 + t] = lg[t] - m - logf(se);
    }
}

// ---------------- workspace layout (bytes) ----------------
// Parity: agg always A0 -> A1 (y), gemm A1 -> A0 (x). x3 ends in A0; y2 (A1) dead after
// the L2 gemm, so hist/parts reuse the A1 region (hist zeroed by mid-stream memset).
// INDEG..DEGS contiguous -> single 449,664 B memset.
constexpr size_t A0_OFF     = 0;                    // 38,400,384 (incl zero row NN)
constexpr size_t A1_OFF     = 38400384;             // 38,400,000: slot -> y -> hist/partials
constexpr size_t HIST_REL   = 0;                    // 12,812,288 (64*50048*4)
constexpr size_t PARTS_REL  = 12812288;             // 19,218,432 (391*12288*4) -> ends 32,030,720
constexpr size_t CSR_OFF    = 76800384;             // 6,400,000
constexpr size_t OFFS_OFF   = 83200384;             // 400,128
constexpr size_t INDEG_OFF  = 83600512;             // 400,000
constexpr size_t SUMS_OFF   = 84000512;             // 49,152
constexpr size_t CNT_OFF    = 84049664;             // 256
constexpr size_t DEGS_OFF   = 84049920;             // 256 -> zero-region ends 84,050,176
constexpr size_t PART_OFF   = 84050176;             // 512
constexpr size_t NSTART_OFF = 84050688;             // 256
constexpr size_t WT0_OFF    = 84050944;             // 49,152
constexpr size_t WT1_OFF    = 84100096;             // 73,728
constexpr size_t WT2_OFF    = 84173824;             // 73,728 -> ends 84,247,552

extern "C" void kernel_launch(void* const* d_in, const int* in_sizes, int n_in,
                              void* d_out, int out_size, void* d_ws, size_t ws_size,
                              hipStream_t stream) {
    const float* x   = (const float*)d_in[0];
    const float* W0  = (const float*)d_in[1];
    const float* b0  = (const float*)d_in[2];
    const float* W1  = (const float*)d_in[3];
    const float* b1  = (const float*)d_in[4];
    const float* W2  = (const float*)d_in[5];
    const float* b2  = (const float*)d_in[6];
    const float* W3  = (const float*)d_in[7];
    const float* b3  = (const float*)d_in[8];
    const float* Wfc = (const float*)d_in[9];
    const float* bfc = (const float*)d_in[10];
    const int*   ei  = (const int*)d_in[11];
    const int*   bat = (const int*)d_in[12];
    float* out = (float*)d_out;

    char* ws = (char*)d_ws;
    unsigned short* A0  = (unsigned short*)(ws + A0_OFF);
    unsigned short* A1  = (unsigned short*)(ws + A1_OFF);
    int* slot   = (int*)(ws + A1_OFF);
    unsigned int* hist  = (unsigned int*)(ws + A1_OFF + HIST_REL);
    float* parts        = (float*)(ws + A1_OFF + PARTS_REL);
    int* csr    = (int*)(ws + CSR_OFF);
    int* offs   = (int*)(ws + OFFS_OFF);
    int* indeg  = (int*)(ws + INDEG_OFF);
    int* part   = (int*)(ws + PART_OFF);
    int* nstart = (int*)(ws + NSTART_OFF);
    unsigned short* Wt0 = (unsigned short*)(ws + WT0_OFF);
    unsigned short* Wt1 = (unsigned short*)(ws + WT1_OFF);
    unsigned short* Wt2 = (unsigned short*)(ws + WT2_OFF);
    float* sums   = (float*)(ws + SUMS_OFF);
    float* cnt    = (float*)(ws + CNT_OFF);
    float* degsum = (float*)(ws + DEGS_OFF);

    // one memset: indeg + sums + cnt + degsum (contiguous 449,664 B)
    hipMemsetAsync(ws + INDEG_OFF, 0, 449664, stream);

    // fused preprocessing (indeg section first: atomics hide under convx streaming)
    k_prep<<<PREP_GRID, 256, 0, stream>>>(x, ei, bat, W0, W1, W2, A0, indeg, slot,
                                          Wt0, Wt1, Wt2, nstart);

    // block-local scan + block-partial scan (consumers add part[])
    k_scan1<<<NB_SCAN, 1024, 0, stream>>>(indeg, offs, part);
    k_scan2<<<1, 128, 0, stream>>>(offs, part);
    k_fill<<<(NE / 4 + 255) / 256, 256, 0, stream>>>(ei, offs, part, slot, csr);

    const int AGG_GRID  = NN / 4;                   // 25000 blocks
    const int GEMM_GRID = (NN / 32 + 3) / 4;        // 782 blocks

    // layers 0..2 (agg A0 -> A1, gemm A1 -> A0)
    k_agg128<<<AGG_GRID, 256, 0, stream>>>(A0, A1, offs, part, indeg, csr);
    k_gemm<128, 192><<<GEMM_GRID, 256, 0, stream>>>(A1, Wt0, b0, A0);
    k_agg192<<<AGG_GRID, 256, 0, stream>>>(A0, A1, offs, part, indeg, csr);
    k_gemm<192, 192><<<GEMM_GRID, 256, 0, stream>>>(A1, Wt1, b1, A0);
    k_agg192<<<AGG_GRID, 256, 0, stream>>>(A0, A1, offs, part, indeg, csr);
    k_gemm<192, 192><<<GEMM_GRID, 256, 0, stream>>>(A1, Wt2, b2, A0);   // x3 -> A0

    // layer 3 via linearity: pooled(y3) = pooled(x3) + eps*degsum + E @ relu(x3)
    hipMemsetAsync(ws + A1_OFF + HIST_REL, 0, 12812288, stream);        // y2 dead; reuse A1
    k_histpool<<<2256, 256, 0, stream>>>(csr, offs, part, nstart, hist, A0, bat, indeg,
                                         sums, cnt, degsum);
    k_egemm<<<EG_BLOCKS, 384, 0, stream>>>(A0, hist, parts);
    k_head<<<NG, 192, 0, stream>>>(sums, parts, cnt, degsum, W3, b3, Wfc, bfc, out);
}